// Round 1
// baseline (13253.400 us; speedup 1.0000x reference)
//
#include <hip/hip_runtime.h>

// Problem constants (fixed by the reference)
#define M_ROWS 106496   // 4096*26  (n,v) rows
#define NBATCH 4096
#define VN 26
#define CDIM 256
#define KNUM 3
#define TS 25

typedef unsigned short u16;
typedef __attribute__((ext_vector_type(8))) short v8s;
typedef __attribute__((ext_vector_type(4))) float v4f;

__device__ __forceinline__ u16 f2bf(float f) {
    unsigned u = __float_as_uint(f);
    u += 0x7FFF + ((u >> 16) & 1);   // RNE
    return (u16)(u >> 16);
}
__device__ __forceinline__ float bf2f(u16 h) {
    return __uint_as_float(((unsigned)h) << 16);
}
__device__ __forceinline__ float sigm(float x) {
    return 1.f / (1.f + __expf(-x));
}
__device__ __forceinline__ float tanh_fast(float x) {
    // 2*sigmoid(2x)-1 ; safe at +-inf of expf
    return 2.f / (1.f + __expf(-2.f * x)) - 1.f;
}

// ---------------------------------------------------------------------------
// Generic NT gemm: C[M,nc] = A[M,256](bf16) @ Bt[nc,256](bf16)^T + bias, bf16 out
// BM=128, BN=128, BK=32; 256 threads = 4 waves (2x2), each wave 64x64.
// ACT=0: bias only. ACT=1: bias + leaky_relu(0.1).
// ---------------------------------------------------------------------------
template <int ACT>
__global__ __launch_bounds__(256) void gemm_nt(
    const u16* __restrict__ A, const u16* __restrict__ Bt,
    const float* __restrict__ bias, u16* __restrict__ C, int nc)
{
    __shared__ u16 Al[128 * 32];
    __shared__ u16 Bl[128 * 32];
    const int m0 = blockIdx.x * 128;
    const int n0 = blockIdx.y * 128;
    const int tid = threadIdx.x;
    const int wid = tid >> 6, lane = tid & 63;
    const int ln = lane & 15, q = lane >> 4;
    const int wm = (wid >> 1) * 64, wn = (wid & 1) * 64;

    v4f acc[4][4] = {};
    for (int k0 = 0; k0 < 256; k0 += 32) {
#pragma unroll
        for (int p = 0; p < 2; ++p) {
            int idx = p * 256 + tid;
            int row = idx >> 2, part = idx & 3;
            *(uint4*)&Al[row * 32 + part * 8] =
                *(const uint4*)&A[(size_t)(m0 + row) * 256 + k0 + part * 8];
            *(uint4*)&Bl[row * 32 + part * 8] =
                *(const uint4*)&Bt[(size_t)(n0 + row) * 256 + k0 + part * 8];
        }
        __syncthreads();
        v8s af[4], bfv[4];
#pragma unroll
        for (int i = 0; i < 4; ++i)
            af[i] = *(const v8s*)&Al[(wm + i * 16 + ln) * 32 + q * 8];
#pragma unroll
        for (int j = 0; j < 4; ++j)
            bfv[j] = *(const v8s*)&Bl[(wn + j * 16 + ln) * 32 + q * 8];
#pragma unroll
        for (int i = 0; i < 4; ++i)
#pragma unroll
            for (int j = 0; j < 4; ++j)
                acc[i][j] = __builtin_amdgcn_mfma_f32_16x16x32_bf16(
                    af[i], bfv[j], acc[i][j], 0, 0, 0);
        __syncthreads();
    }
#pragma unroll
    for (int i = 0; i < 4; ++i)
#pragma unroll
        for (int j = 0; j < 4; ++j) {
            int gc = n0 + wn + j * 16 + ln;
            float b = bias[gc];
#pragma unroll
            for (int r = 0; r < 4; ++r) {
                int gr = m0 + wm + i * 16 + q * 4 + r;
                float v = acc[i][j][r] + b;
                if (ACT) v = v > 0.f ? v : 0.1f * v;
                C[(size_t)gr * nc + gc] = f2bf(v);
            }
        }
}

// ---------------------------------------------------------------------------
// Graph mix: msg[(n,w),c] = sum_{k,v} y[(n,v),k*256+c] * aadj[k][v][w]
// One block per n. aadj read from GLOBAL with wave-uniform indices -> s_loads.
// ---------------------------------------------------------------------------
__global__ __launch_bounds__(256) void graph_mix(
    const u16* __restrict__ y, const float* __restrict__ aadj,
    u16* __restrict__ msg)
{
    __shared__ u16 yl[VN * 768];
    const int n = blockIdx.x, tid = threadIdx.x;
    const uint4* src = (const uint4*)(y + (size_t)n * VN * 768);
    for (int idx = tid; idx < VN * 768 / 8; idx += 256)
        ((uint4*)yl)[idx] = src[idx];
    __syncthreads();
    const int c = tid;
    float acc[VN] = {};
    for (int k = 0; k < KNUM; ++k)
        for (int v = 0; v < VN; ++v) {
            float yv = bf2f(yl[v * 768 + k * 256 + c]);
            const float* ap = &aadj[(k * VN + v) * VN];
#pragma unroll
            for (int w = 0; w < VN; ++w) acc[w] += yv * ap[w];
        }
    size_t base = (size_t)n * VN * 256;
    for (int w = 0; w < VN; ++w) msg[base + w * 256 + c] = f2bf(acc[w]);
}

// ---------------------------------------------------------------------------
// Fused GRU: computes m@{Whr,Whi,Whh}^T for a 128x64 tile (3 accumulators
// sharing the A tile), then x-projection + gates + hnew in the epilogue.
// grid = (832, 4): n0 = by*64 covers the 256 hidden cols.
// ---------------------------------------------------------------------------
__global__ __launch_bounds__(256) void gru_fused(
    const u16* __restrict__ Am, const u16* __restrict__ hprev,
    u16* __restrict__ hout, const u16* __restrict__ wcat,
    const float* __restrict__ xw, const float* __restrict__ xb,
    const float* __restrict__ p1, const float* __restrict__ p2,
    const float* __restrict__ p3)
{
    __shared__ u16 Al[128 * 32];        // 8 KB
    __shared__ u16 Bl[3 * 64 * 32];     // 12 KB
    __shared__ float xf[128 * 9];       // 4.6 KB
    __shared__ float xwl[3 * 64 * 9];   // 6.9 KB
    __shared__ float xbl[3 * 64];
    const int m0 = blockIdx.x * 128;
    const int n0 = blockIdx.y * 64;
    const int tid = threadIdx.x;

    if (tid < 128) {
        int m = m0 + tid;
        float a0 = p1[m * 3 + 0], a1 = p1[m * 3 + 1], a2 = p1[m * 3 + 2];
        float b0 = p2[m * 3 + 0], b1 = p2[m * 3 + 1], b2 = p2[m * 3 + 2];
        float c0 = p3[m * 3 + 0], c1 = p3[m * 3 + 1], c2 = p3[m * 3 + 2];
        float* xr = &xf[tid * 9];
        xr[0] = a0; xr[1] = a1; xr[2] = a2;                      // ins_p
        xr[3] = b0 - c0; xr[4] = b1 - c1; xr[5] = b2 - c2;       // ins_v
        xr[6] = a0 - 2.f * b0 + c0;                               // ins_a
        xr[7] = a1 - 2.f * b1 + c1;
        xr[8] = a2 - 2.f * b2 + c2;
    }
    for (int idx = tid; idx < 3 * 64 * 9; idx += 256) {
        int g = idx / 576, off = idx % 576;
        xwl[idx] = xw[g * 2304 + n0 * 9 + off];
    }
    if (tid < 192) {
        int g = tid >> 6, cl = tid & 63;
        xbl[tid] = xb[g * 256 + n0 + cl];
    }

    const int wid = tid >> 6, lane = tid & 63;
    const int ln = lane & 15, q = lane >> 4;
    const int wm = (wid >> 1) * 64, wn = (wid & 1) * 32;
    v4f accr[4][2] = {}, accz[4][2] = {}, acch[4][2] = {};

    for (int k0 = 0; k0 < 256; k0 += 32) {
#pragma unroll
        for (int p = 0; p < 2; ++p) {
            int idx = p * 256 + tid;
            int row = idx >> 2, part = idx & 3;
            *(uint4*)&Al[row * 32 + part * 8] =
                *(const uint4*)&Am[(size_t)(m0 + row) * 256 + k0 + part * 8];
        }
#pragma unroll
        for (int p = 0; p < 3; ++p) {
            int idx = p * 256 + tid;
            int row = idx >> 2, part = idx & 3;   // row 0..191
            int g = row >> 6, rl = row & 63;
            *(uint4*)&Bl[row * 32 + part * 8] =
                *(const uint4*)&wcat[(size_t)(g * 256 + n0 + rl) * 256 + k0 + part * 8];
        }
        __syncthreads();
        v8s af[4];
#pragma unroll
        for (int i = 0; i < 4; ++i)
            af[i] = *(const v8s*)&Al[(wm + i * 16 + ln) * 32 + q * 8];
        v8s bfr[3][2];
#pragma unroll
        for (int g = 0; g < 3; ++g)
#pragma unroll
            for (int j = 0; j < 2; ++j)
                bfr[g][j] = *(const v8s*)&Bl[(g * 64 + wn + j * 16 + ln) * 32 + q * 8];
#pragma unroll
        for (int i = 0; i < 4; ++i)
#pragma unroll
            for (int j = 0; j < 2; ++j) {
                accr[i][j] = __builtin_amdgcn_mfma_f32_16x16x32_bf16(af[i], bfr[0][j], accr[i][j], 0, 0, 0);
                accz[i][j] = __builtin_amdgcn_mfma_f32_16x16x32_bf16(af[i], bfr[1][j], accz[i][j], 0, 0, 0);
                acch[i][j] = __builtin_amdgcn_mfma_f32_16x16x32_bf16(af[i], bfr[2][j], acch[i][j], 0, 0, 0);
            }
        __syncthreads();
    }

#pragma unroll
    for (int i = 0; i < 4; ++i)
#pragma unroll
        for (int j = 0; j < 2; ++j) {
            int cl64 = wn + j * 16 + ln;
            int gc = n0 + cl64;
#pragma unroll
            for (int r = 0; r < 4; ++r) {
                int rl = wm + i * 16 + q * 4 + r;
                int gr = m0 + rl;
                float xr = xbl[cl64], xz = xbl[64 + cl64], xn = xbl[128 + cl64];
#pragma unroll
                for (int t9 = 0; t9 < 9; ++t9) {
                    float xv = xf[rl * 9 + t9];
                    xr += xv * xwl[cl64 * 9 + t9];
                    xz += xv * xwl[576 + cl64 * 9 + t9];
                    xn += xv * xwl[1152 + cl64 * 9 + t9];
                }
                float rg = sigm(xr + accr[i][j][r]);
                float zg = sigm(xz + accz[i][j][r]);
                float nn = tanh_fast(xn + rg * acch[i][j][r]);
                float hp = bf2f(hprev[(size_t)gr * 256 + gc]);
                hout[(size_t)gr * 256 + gc] = f2bf((1.f - zg) * nn + zg * hp);
            }
        }
}

// ---------------------------------------------------------------------------
// Head: res = hd2 @ W3^T + b3 ; pred = h1 + res ; write out[:, s] and pnew.
// One block per 32 rows.
// ---------------------------------------------------------------------------
__global__ __launch_bounds__(256) void head_out(
    const u16* __restrict__ hd2, const float* __restrict__ w3,
    const float* __restrict__ b3, const float* __restrict__ p1,
    float* __restrict__ pnew, float* __restrict__ out, int s)
{
    __shared__ u16 hl[32 * 256];
    __shared__ float w3l[3 * 256];
    const int bm = blockIdx.x, tid = threadIdx.x;
    const uint4* src = (const uint4*)(hd2 + (size_t)bm * 32 * 256);
    for (int idx = tid; idx < 1024; idx += 256) ((uint4*)hl)[idx] = src[idx];
    for (int idx = tid; idx < 768; idx += 256) w3l[idx] = w3[idx];
    __syncthreads();
    const int r = tid >> 3, l8 = tid & 7;
    float s0 = 0.f, s1 = 0.f, s2 = 0.f;
    for (int c = l8 * 32; c < l8 * 32 + 32; ++c) {
        float hv = bf2f(hl[r * 256 + c]);
        s0 += hv * w3l[c];
        s1 += hv * w3l[256 + c];
        s2 += hv * w3l[512 + c];
    }
    for (int off = 1; off < 8; off <<= 1) {
        s0 += __shfl_xor(s0, off, 8);
        s1 += __shfl_xor(s1, off, 8);
        s2 += __shfl_xor(s2, off, 8);
    }
    if (l8 == 0) {
        int m = bm * 32 + r;
        float o0 = p1[m * 3 + 0] + s0 + b3[0];
        float o1 = p1[m * 3 + 1] + s1 + b3[1];
        float o2 = p1[m * 3 + 2] + s2 + b3[2];
        size_t ob = ((size_t)m * TS + s) * 3;
        out[ob + 0] = o0; out[ob + 1] = o1; out[ob + 2] = o2;
        pnew[m * 3 + 0] = o0; pnew[m * 3 + 1] = o1; pnew[m * 3 + 2] = o2;
    }
}

// ---------------------------------------------------------------------------
// hidden [N,C,V] fp32 -> h[(n,v),c] bf16. One block per n.
// ---------------------------------------------------------------------------
__global__ __launch_bounds__(256) void transpose_h(
    const float* __restrict__ hidden, u16* __restrict__ hA)
{
    __shared__ float hl[256 * VN];
    const int n = blockIdx.x, tid = threadIdx.x;
    const uint4* src = (const uint4*)(hidden + (size_t)n * 256 * VN);
    for (int idx = tid; idx < 256 * VN / 4; idx += 256)
        ((uint4*)hl)[idx] = src[idx];
    __syncthreads();
    size_t base = (size_t)n * VN * 256;
    for (int idx = tid; idx < VN * 256; idx += 256) {
        int v = idx >> 8, c = idx & 255;
        hA[base + idx] = f2bf(hl[c * VN + v]);
    }
}

// ---------------------------------------------------------------------------
// Weight packing (once per call): bf16 casts + A_adj + small fp32 copies.
// ---------------------------------------------------------------------------
__global__ __launch_bounds__(256) void pack_weights(
    const float* __restrict__ Whr, const float* __restrict__ Whi,
    const float* __restrict__ Whh, const float* __restrict__ convw_f,
    const float* __restrict__ W1f, const float* __restrict__ W2f,
    const float* __restrict__ Af, const float* __restrict__ emul,
    const float* __restrict__ eadd, const float* __restrict__ Wir,
    const float* __restrict__ Wii, const float* __restrict__ Win,
    const float* __restrict__ bir, const float* __restrict__ bii,
    const float* __restrict__ b_in, const float* __restrict__ convb_f,
    const float* __restrict__ b1f, const float* __restrict__ b2f,
    const float* __restrict__ W3f, const float* __restrict__ b3f,
    u16* __restrict__ wcat, u16* __restrict__ convw, u16* __restrict__ w1,
    u16* __restrict__ w2, float* __restrict__ aadj, float* __restrict__ xw,
    float* __restrict__ xb, float* __restrict__ convb, float* __restrict__ b1,
    float* __restrict__ b2, float* __restrict__ w3, float* __restrict__ b3)
{
    int gid = blockIdx.x * 256 + threadIdx.x;
    int stride = gridDim.x * 256;
    for (int i = gid; i < 65536; i += stride) {
        wcat[i] = f2bf(Whr[i]);
        wcat[65536 + i] = f2bf(Whi[i]);
        wcat[131072 + i] = f2bf(Whh[i]);
        w1[i] = f2bf(W1f[i]);
        w2[i] = f2bf(W2f[i]);
    }
    for (int i = gid; i < 196608; i += stride) convw[i] = f2bf(convw_f[i]);
    for (int i = gid; i < KNUM * VN * VN; i += stride)
        aadj[i] = Af[i] * emul[i] + eadd[i];
    for (int i = gid; i < 2304; i += stride) {
        xw[i] = Wir[i]; xw[2304 + i] = Wii[i]; xw[4608 + i] = Win[i];
    }
    for (int i = gid; i < 256; i += stride) {
        xb[i] = bir[i]; xb[256 + i] = bii[i]; xb[512 + i] = b_in[i];
        b1[i] = b1f[i]; b2[i] = b2f[i];
    }
    for (int i = gid; i < 768; i += stride) { convb[i] = convb_f[i]; w3[i] = W3f[i]; }
    if (gid < 3) b3[gid] = b3f[gid];
}

// ---------------------------------------------------------------------------
extern "C" void kernel_launch(void* const* d_in, const int* in_sizes, int n_in,
                              void* d_out, int out_size, void* d_ws, size_t ws_size,
                              hipStream_t stream)
{
    const float* inputs   = (const float*)d_in[0];
    const float* inputs_p = (const float*)d_in[1];
    const float* inputs_p2= (const float*)d_in[2];
    const float* hidden   = (const float*)d_in[3];
    const float* Af       = (const float*)d_in[4];
    const float* emul     = (const float*)d_in[5];
    const float* eadd     = (const float*)d_in[6];
    const float* conv_w   = (const float*)d_in[7];
    const float* conv_b   = (const float*)d_in[8];
    const float* Wir      = (const float*)d_in[9];
    const float* bir      = (const float*)d_in[10];
    const float* Wii      = (const float*)d_in[11];
    const float* bii      = (const float*)d_in[12];
    const float* Win      = (const float*)d_in[13];
    const float* b_in     = (const float*)d_in[14];
    const float* Whr      = (const float*)d_in[15];
    const float* Whi      = (const float*)d_in[16];
    const float* Whh      = (const float*)d_in[17];
    const float* W1f      = (const float*)d_in[18];
    const float* b1f      = (const float*)d_in[19];
    const float* W2f      = (const float*)d_in[20];
    const float* b2f      = (const float*)d_in[21];
    const float* W3f      = (const float*)d_in[22];
    const float* b3f      = (const float*)d_in[23];
    float* out = (float*)d_out;

    const size_t M = M_ROWS;
    char* ws = (char*)d_ws;
    size_t off = 0;
    auto alloc = [&](size_t bytes) -> void* {
        void* p = ws + off;
        off = (off + bytes + 255) & ~(size_t)255;
        return p;
    };
    u16* hA    = (u16*)alloc(M * 256 * 2);
    u16* hB    = (u16*)alloc(M * 256 * 2);
    u16* msg   = (u16*)alloc(M * 256 * 2);
    u16* ybuf  = (u16*)alloc(M * 768 * 2);
    float* pa  = (float*)alloc(M * 3 * 4);
    float* pb  = (float*)alloc(M * 3 * 4);
    float* pc  = (float*)alloc(M * 3 * 4);
    u16* wcat  = (u16*)alloc(3 * 65536 * 2);
    u16* convw = (u16*)alloc(196608 * 2);
    u16* w1    = (u16*)alloc(65536 * 2);
    u16* w2    = (u16*)alloc(65536 * 2);
    float* aadj  = (float*)alloc(KNUM * VN * VN * 4);
    float* xw    = (float*)alloc(3 * 2304 * 4);
    float* xb    = (float*)alloc(768 * 4);
    float* convb = (float*)alloc(768 * 4);
    float* b1    = (float*)alloc(256 * 4);
    float* b2    = (float*)alloc(256 * 4);
    float* w3    = (float*)alloc(768 * 4);
    float* b3    = (float*)alloc(16);
    if (off > ws_size) return;  // workspace too small -> fail loudly

    pack_weights<<<512, 256, 0, stream>>>(
        Whr, Whi, Whh, conv_w, W1f, W2f, Af, emul, eadd, Wir, Wii, Win,
        bir, bii, b_in, conv_b, b1f, b2f, W3f, b3f,
        wcat, convw, w1, w2, aadj, xw, xb, convb, b1, b2, w3, b3);
    transpose_h<<<NBATCH, 256, 0, stream>>>(hidden, hA);
    hipMemcpyAsync(pa, inputs,    M * 3 * 4, hipMemcpyDeviceToDevice, stream);
    hipMemcpyAsync(pb, inputs_p,  M * 3 * 4, hipMemcpyDeviceToDevice, stream);
    hipMemcpyAsync(pc, inputs_p2, M * 3 * 4, hipMemcpyDeviceToDevice, stream);

    u16* hcur = hA;  u16* hnext = hB;
    float* P1 = pa;  float* P2 = pb;  float* P3 = pc;
    u16* hd  = ybuf;
    u16* hd2 = ybuf + M * 256;
    const int MB = M_ROWS / 128;  // 832

    for (int s = 0; s < TS; ++s) {
        const u16* m_ptr;
        if (s < 10) {
            gemm_nt<0><<<dim3(MB, 6), 256, 0, stream>>>(hcur, convw, convb, ybuf, 768);
            graph_mix<<<NBATCH, 256, 0, stream>>>(ybuf, aadj, msg);
            m_ptr = msg;
        } else {
            m_ptr = hcur;
        }
        gru_fused<<<dim3(MB, 4), 256, 0, stream>>>(m_ptr, hcur, hnext, wcat,
                                                   xw, xb, P1, P2, P3);
        gemm_nt<1><<<dim3(MB, 2), 256, 0, stream>>>(hnext, w1, b1, hd, 256);
        gemm_nt<1><<<dim3(MB, 2), 256, 0, stream>>>(hd, w2, b2, hd2, 256);
        head_out<<<M_ROWS / 32, 256, 0, stream>>>(hd2, w3, b3, P1, P3, out, s);
        // rotate history: (h1,h2,h3) <- (pred(old h3 buf), old h1, old h2)
        float* t = P3; P3 = P2; P2 = P1; P1 = t;
        u16* ht = hcur; hcur = hnext; hnext = ht;
    }
}

// Round 2
// 7026.838 us; speedup vs baseline: 1.8861x; 1.8861x over previous
//
#include <hip/hip_runtime.h>

// Problem constants (fixed by the reference)
#define M_ROWS 106496   // 4096*26  (n,v) rows
#define NBATCH 4096
#define VN 26
#define KNUM 3
#define TS 25

typedef unsigned short u16;
typedef __attribute__((ext_vector_type(8))) short v8s;
typedef __attribute__((ext_vector_type(4))) float v4f;

__device__ __forceinline__ u16 f2bf(float f) {
    unsigned u = __float_as_uint(f);
    u += 0x7FFF + ((u >> 16) & 1);   // RNE
    return (u16)(u >> 16);
}
__device__ __forceinline__ float bf2f(u16 h) {
    return __uint_as_float(((unsigned)h) << 16);
}
__device__ __forceinline__ float sigm(float x) {
    return 1.f / (1.f + __expf(-x));
}
__device__ __forceinline__ float tanh_fast(float x) {
    return 2.f / (1.f + __expf(-2.f * x)) - 1.f;
}

// Async global->LDS, 16B per lane. LDS dest must be the wave-uniform base;
// HW adds lane*16. Our staging layout is contiguous in lane order by design.
typedef const __attribute__((address_space(1))) unsigned int* gas_t;
typedef __attribute__((address_space(3))) unsigned int* las_t;
__device__ __forceinline__ void gl16(const void* g, void* l) {
    __builtin_amdgcn_global_load_lds((gas_t)g, (las_t)l, 16, 0, 0);
}

// ---------------------------------------------------------------------------
// Generic NT gemm: C[M,nc] = A[M,256](bf16) @ Bt[nc,256](bf16)^T + bias
// BM=128, BN=128, BK=32; 256 threads = 4 waves (2x2), each wave 64x64.
// ACT=0: bias only. ACT=1: bias + leaky_relu(0.1).
// ---------------------------------------------------------------------------
template <int ACT>
__global__ __launch_bounds__(256) void gemm_nt(
    const u16* __restrict__ A, const u16* __restrict__ Bt,
    const float* __restrict__ bias, u16* __restrict__ C, int nc)
{
    __shared__ u16 Al[128 * 32];
    __shared__ u16 Bl[128 * 32];
    const int m0 = blockIdx.x * 128;
    const int n0 = blockIdx.y * 128;
    const int tid = threadIdx.x;
    const int wid = tid >> 6, lane = tid & 63;
    const int ln = lane & 15, q = lane >> 4;
    const int wm = (wid >> 1) * 64, wn = (wid & 1) * 64;
    const int srow = tid >> 2, spart = tid & 3;

    v4f acc[4][4] = {};
    for (int k0 = 0; k0 < 256; k0 += 32) {
#pragma unroll
        for (int p = 0; p < 2; ++p) {
            gl16(&A[(size_t)(m0 + p * 64 + srow) * 256 + k0 + spart * 8],
                 &Al[(p * 256 + wid * 64) * 8]);
            gl16(&Bt[(size_t)(n0 + p * 64 + srow) * 256 + k0 + spart * 8],
                 &Bl[(p * 256 + wid * 64) * 8]);
        }
        __syncthreads();
        v8s af[4], bfv[4];
#pragma unroll
        for (int i = 0; i < 4; ++i)
            af[i] = *(const v8s*)&Al[(wm + i * 16 + ln) * 32 + q * 8];
#pragma unroll
        for (int j = 0; j < 4; ++j)
            bfv[j] = *(const v8s*)&Bl[(wn + j * 16 + ln) * 32 + q * 8];
#pragma unroll
        for (int i = 0; i < 4; ++i)
#pragma unroll
            for (int j = 0; j < 4; ++j)
                acc[i][j] = __builtin_amdgcn_mfma_f32_16x16x32_bf16(
                    af[i], bfv[j], acc[i][j], 0, 0, 0);
        __syncthreads();
    }
#pragma unroll
    for (int i = 0; i < 4; ++i)
#pragma unroll
        for (int j = 0; j < 4; ++j) {
            int gc = n0 + wn + j * 16 + ln;
            float b = bias[gc];
#pragma unroll
            for (int r = 0; r < 4; ++r) {
                int gr = m0 + wm + i * 16 + q * 4 + r;
                float v = acc[i][j][r] + b;
                if (ACT) v = v > 0.f ? v : 0.1f * v;
                C[(size_t)gr * nc + gc] = f2bf(v);
            }
        }
}

// ---------------------------------------------------------------------------
// Graph mix: msg[(n,w),c] = sum_{k,v} y[(n,v),k*256+c] * aadj[k][v][w]
// ---------------------------------------------------------------------------
__global__ __launch_bounds__(256) void graph_mix(
    const u16* __restrict__ y, const float* __restrict__ aadj,
    u16* __restrict__ msg)
{
    __shared__ u16 yl[VN * 768];
    const int n = blockIdx.x, tid = threadIdx.x;
    const uint4* src = (const uint4*)(y + (size_t)n * VN * 768);
    for (int idx = tid; idx < VN * 768 / 8; idx += 256)
        ((uint4*)yl)[idx] = src[idx];
    __syncthreads();
    const int c = tid;
    float acc[VN] = {};
    for (int k = 0; k < KNUM; ++k)
        for (int v = 0; v < VN; ++v) {
            float yv = bf2f(yl[v * 768 + k * 256 + c]);
            const float* ap = &aadj[(k * VN + v) * VN];
#pragma unroll
            for (int w = 0; w < VN; ++w) acc[w] += yv * ap[w];
        }
    size_t base = (size_t)n * VN * 256;
    for (int w = 0; w < VN; ++w) msg[base + w * 256 + c] = f2bf(acc[w]);
}

// ---------------------------------------------------------------------------
// Fused GRU, K=288: cols 0..255 = msg (Wh*), 256..287 = xpad (x-proj + bias).
// r,z gates fully folded into accumulators; n-gate x-part in a 4th acc fed by
// one extra MFMA against wxn (x@Win + b_in must stay outside r*(m@Whh)).
// grid = (832, 4); block = 128 rows x 64 cols x 3 gates.
// ---------------------------------------------------------------------------
__global__ __launch_bounds__(256) void gru_fused(
    const u16* __restrict__ Am, const u16* __restrict__ xpad,
    const u16* __restrict__ hprev, u16* __restrict__ hout,
    const u16* __restrict__ wfull, const u16* __restrict__ wxn)
{
    __shared__ u16 Al[128 * 32];   // 8 KB
    __shared__ u16 Bl[192 * 32];   // 12 KB
    __shared__ u16 Xl[64 * 32];    // 4 KB
    const int m0 = blockIdx.x * 128;
    const int n0 = blockIdx.y * 64;
    const int tid = threadIdx.x;
    const int wid = tid >> 6, lane = tid & 63;
    const int ln = lane & 15, q = lane >> 4;
    const int wm = (wid >> 1) * 64, wn = (wid & 1) * 32;
    const int srow = tid >> 2, spart = tid & 3;

    // wxn tile (64 rows of this block's n0 slice), needed only at kt==8
    gl16(&wxn[(size_t)(n0 + srow) * 32 + spart * 8], &Xl[(wid * 64) * 8]);

    v4f accr[4][2] = {}, accz[4][2] = {}, acch[4][2] = {}, accn[4][2] = {};

    for (int kt = 0; kt < 9; ++kt) {
#pragma unroll
        for (int p = 0; p < 2; ++p) {
            const u16* ga = (kt < 8)
                ? &Am[(size_t)(m0 + p * 64 + srow) * 256 + kt * 32 + spart * 8]
                : &xpad[(size_t)(m0 + p * 64 + srow) * 32 + spart * 8];
            gl16(ga, &Al[(p * 256 + wid * 64) * 8]);
        }
#pragma unroll
        for (int p = 0; p < 3; ++p)
            gl16(&wfull[(size_t)(p * 256 + n0 + srow) * 288 + kt * 32 + spart * 8],
                 &Bl[(p * 256 + wid * 64) * 8]);
        __syncthreads();

        v8s af[4];
#pragma unroll
        for (int i = 0; i < 4; ++i)
            af[i] = *(const v8s*)&Al[(wm + i * 16 + ln) * 32 + q * 8];
        v8s bfr[3][2];
#pragma unroll
        for (int g = 0; g < 3; ++g)
#pragma unroll
            for (int j = 0; j < 2; ++j)
                bfr[g][j] = *(const v8s*)&Bl[(g * 64 + wn + j * 16 + ln) * 32 + q * 8];
#pragma unroll
        for (int i = 0; i < 4; ++i)
#pragma unroll
            for (int j = 0; j < 2; ++j) {
                accr[i][j] = __builtin_amdgcn_mfma_f32_16x16x32_bf16(af[i], bfr[0][j], accr[i][j], 0, 0, 0);
                accz[i][j] = __builtin_amdgcn_mfma_f32_16x16x32_bf16(af[i], bfr[1][j], accz[i][j], 0, 0, 0);
                acch[i][j] = __builtin_amdgcn_mfma_f32_16x16x32_bf16(af[i], bfr[2][j], acch[i][j], 0, 0, 0);
            }
        if (kt == 8) {
            v8s bfn[2];
#pragma unroll
            for (int j = 0; j < 2; ++j)
                bfn[j] = *(const v8s*)&Xl[(wn + j * 16 + ln) * 32 + q * 8];
#pragma unroll
            for (int i = 0; i < 4; ++i)
#pragma unroll
                for (int j = 0; j < 2; ++j)
                    accn[i][j] = __builtin_amdgcn_mfma_f32_16x16x32_bf16(af[i], bfn[j], accn[i][j], 0, 0, 0);
        }
        __syncthreads();
    }

#pragma unroll
    for (int i = 0; i < 4; ++i)
#pragma unroll
        for (int j = 0; j < 2; ++j) {
            int gc = n0 + wn + j * 16 + ln;
#pragma unroll
            for (int r = 0; r < 4; ++r) {
                int gr = m0 + wm + i * 16 + q * 4 + r;
                float rg = sigm(accr[i][j][r]);
                float zg = sigm(accz[i][j][r]);
                float nn = tanh_fast(accn[i][j][r] + rg * acch[i][j][r]);
                float hp = bf2f(hprev[(size_t)gr * 256 + gc]);
                hout[(size_t)gr * 256 + gc] = f2bf((1.f - zg) * nn + zg * hp);
            }
        }
}

// ---------------------------------------------------------------------------
// Head: res = hd2 @ W3^T + b3 ; pred = h1 + res ; write out[:, s], pnew,
// and next step's xpad row [pred, h2'-h3', pred-2h2'+h3', 1, 0...].
// ---------------------------------------------------------------------------
__global__ __launch_bounds__(256) void head_out(
    const u16* __restrict__ hd2, const float* __restrict__ w3,
    const float* __restrict__ b3, const float* __restrict__ p1,
    const float* __restrict__ p2, float* __restrict__ pnew,
    u16* __restrict__ xpad, float* __restrict__ out, int s)
{
    __shared__ u16 hl[32 * 256];
    __shared__ float w3l[3 * 256];
    const int bm = blockIdx.x, tid = threadIdx.x;
    const uint4* src = (const uint4*)(hd2 + (size_t)bm * 32 * 256);
    for (int idx = tid; idx < 1024; idx += 256) ((uint4*)hl)[idx] = src[idx];
    for (int idx = tid; idx < 768; idx += 256) w3l[idx] = w3[idx];
    __syncthreads();
    const int r = tid >> 3, l8 = tid & 7;
    float s0 = 0.f, s1 = 0.f, s2 = 0.f;
    for (int c = l8 * 32; c < l8 * 32 + 32; ++c) {
        float hv = bf2f(hl[r * 256 + c]);
        s0 += hv * w3l[c];
        s1 += hv * w3l[256 + c];
        s2 += hv * w3l[512 + c];
    }
    for (int off = 1; off < 8; off <<= 1) {
        s0 += __shfl_xor(s0, off, 8);
        s1 += __shfl_xor(s1, off, 8);
        s2 += __shfl_xor(s2, off, 8);
    }
    // butterfly leaves the full sums in ALL 8 lanes
    const int m = bm * 32 + r;
    float a0 = p1[m * 3 + 0], a1 = p1[m * 3 + 1], a2 = p1[m * 3 + 2];
    float c0 = p2[m * 3 + 0], c1 = p2[m * 3 + 1], c2 = p2[m * 3 + 2];
    float o0 = a0 + s0 + b3[0];
    float o1 = a1 + s1 + b3[1];
    float o2 = a2 + s2 + b3[2];
    if (l8 == 0) {
        size_t ob = ((size_t)m * TS + s) * 3;
        out[ob + 0] = o0; out[ob + 1] = o1; out[ob + 2] = o2;
        pnew[m * 3 + 0] = o0; pnew[m * 3 + 1] = o1; pnew[m * 3 + 2] = o2;
    }
    // next x: ins_p=pred, ins_v=p1-p2, ins_a=pred-2*p1+p2, col9=1, rest 0
    u16 xv[4];
#pragma unroll
    for (int t = 0; t < 4; ++t) {
        int c = l8 * 4 + t;
        float v = 0.f;
        if (c == 0) v = o0; else if (c == 1) v = o1; else if (c == 2) v = o2;
        else if (c == 3) v = a0 - c0; else if (c == 4) v = a1 - c1;
        else if (c == 5) v = a2 - c2;
        else if (c == 6) v = o0 - 2.f * a0 + c0;
        else if (c == 7) v = o1 - 2.f * a1 + c1;
        else if (c == 8) v = o2 - 2.f * a2 + c2;
        else if (c == 9) v = 1.f;
        xv[t] = f2bf(v);
    }
    uint2 pk;
    pk.x = (unsigned)xv[0] | ((unsigned)xv[1] << 16);
    pk.y = (unsigned)xv[2] | ((unsigned)xv[3] << 16);
    ((uint2*)&xpad[(size_t)m * 32])[l8] = pk;
}

// ---------------------------------------------------------------------------
// Step-0 xpad from the three input frames.
// ---------------------------------------------------------------------------
__global__ __launch_bounds__(256) void init_xpad(
    const float* __restrict__ x0, const float* __restrict__ xp,
    const float* __restrict__ xp2, u16* __restrict__ xpad)
{
    int m = blockIdx.x * 256 + threadIdx.x;
    float a0 = x0[m * 3 + 0], a1 = x0[m * 3 + 1], a2 = x0[m * 3 + 2];
    float b0 = xp[m * 3 + 0], b1 = xp[m * 3 + 1], b2 = xp[m * 3 + 2];
    float c0 = xp2[m * 3 + 0], c1 = xp2[m * 3 + 1], c2 = xp2[m * 3 + 2];
    unsigned t[32];
#pragma unroll
    for (int i = 0; i < 32; ++i) t[i] = 0;
    t[0] = f2bf(a0); t[1] = f2bf(a1); t[2] = f2bf(a2);
    t[3] = f2bf(b0 - c0); t[4] = f2bf(b1 - c1); t[5] = f2bf(b2 - c2);
    t[6] = f2bf(a0 - 2.f * b0 + c0);
    t[7] = f2bf(a1 - 2.f * b1 + c1);
    t[8] = f2bf(a2 - 2.f * b2 + c2);
    t[9] = f2bf(1.f);
    uint4* dst = (uint4*)&xpad[(size_t)m * 32];
#pragma unroll
    for (int wq = 0; wq < 4; ++wq) {
        uint4 u;
        u.x = t[wq * 8 + 0] | (t[wq * 8 + 1] << 16);
        u.y = t[wq * 8 + 2] | (t[wq * 8 + 3] << 16);
        u.z = t[wq * 8 + 4] | (t[wq * 8 + 5] << 16);
        u.w = t[wq * 8 + 6] | (t[wq * 8 + 7] << 16);
        dst[wq] = u;
    }
}

// ---------------------------------------------------------------------------
// hidden [N,C,V] fp32 -> h[(n,v),c] bf16.
// ---------------------------------------------------------------------------
__global__ __launch_bounds__(256) void transpose_h(
    const float* __restrict__ hidden, u16* __restrict__ hA)
{
    __shared__ float hl[256 * VN];
    const int n = blockIdx.x, tid = threadIdx.x;
    const uint4* src = (const uint4*)(hidden + (size_t)n * 256 * VN);
    for (int idx = tid; idx < 256 * VN / 4; idx += 256)
        ((uint4*)hl)[idx] = src[idx];
    __syncthreads();
    size_t base = (size_t)n * VN * 256;
    for (int idx = tid; idx < VN * 256; idx += 256) {
        int v = idx >> 8, c = idx & 255;
        hA[base + idx] = f2bf(hl[c * VN + v]);
    }
}

// ---------------------------------------------------------------------------
// Weight packing (once per call).
// wfull[768,288]: row g*256+c -> cols 0..255 = Wh_g[c,:],
//   256..264 = x-weights (g<2), 265 = bias (g<2), rest 0.
// wxn[256,32]:   row c -> 0..8 = Win[c,:], 9 = b_in[c], rest 0.
// ---------------------------------------------------------------------------
__global__ __launch_bounds__(256) void pack_weights(
    const float* __restrict__ Whr, const float* __restrict__ Whi,
    const float* __restrict__ Whh, const float* __restrict__ convw_f,
    const float* __restrict__ W1f, const float* __restrict__ W2f,
    const float* __restrict__ Af, const float* __restrict__ emul,
    const float* __restrict__ eadd, const float* __restrict__ Wir,
    const float* __restrict__ Wii, const float* __restrict__ Win,
    const float* __restrict__ bir, const float* __restrict__ bii,
    const float* __restrict__ b_in, const float* __restrict__ convb_f,
    const float* __restrict__ b1f, const float* __restrict__ b2f,
    const float* __restrict__ W3f, const float* __restrict__ b3f,
    u16* __restrict__ wfull, u16* __restrict__ wxn, u16* __restrict__ convw,
    u16* __restrict__ w1, u16* __restrict__ w2, float* __restrict__ aadj,
    float* __restrict__ convb, float* __restrict__ b1, float* __restrict__ b2,
    float* __restrict__ w3, float* __restrict__ b3)
{
    int gid = blockIdx.x * 256 + threadIdx.x;
    int stride = gridDim.x * 256;
    for (int i = gid; i < 768 * 288; i += stride) {
        int row = i / 288, col = i - row * 288;
        int g = row >> 8, c = row & 255;
        float v = 0.f;
        if (col < 256)
            v = (g == 0 ? Whr : (g == 1 ? Whi : Whh))[c * 256 + col];
        else if (col < 265) {
            int tcol = col - 256;
            v = (g == 0 ? Wir[c * 9 + tcol] : (g == 1 ? Wii[c * 9 + tcol] : 0.f));
        } else if (col == 265)
            v = (g == 0 ? bir[c] : (g == 1 ? bii[c] : 0.f));
        wfull[i] = f2bf(v);
    }
    for (int i = gid; i < 256 * 32; i += stride) {
        int c = i >> 5, col = i & 31;
        float v = 0.f;
        if (col < 9) v = Win[c * 9 + col];
        else if (col == 9) v = b_in[c];
        wxn[i] = f2bf(v);
    }
    for (int i = gid; i < 65536; i += stride) {
        w1[i] = f2bf(W1f[i]);
        w2[i] = f2bf(W2f[i]);
    }
    for (int i = gid; i < 196608; i += stride) convw[i] = f2bf(convw_f[i]);
    for (int i = gid; i < KNUM * VN * VN; i += stride)
        aadj[i] = Af[i] * emul[i] + eadd[i];
    for (int i = gid; i < 256; i += stride) { b1[i] = b1f[i]; b2[i] = b2f[i]; }
    for (int i = gid; i < 768; i += stride) { convb[i] = convb_f[i]; w3[i] = W3f[i]; }
    if (gid < 3) b3[gid] = b3f[gid];
}

// ---------------------------------------------------------------------------
extern "C" void kernel_launch(void* const* d_in, const int* in_sizes, int n_in,
                              void* d_out, int out_size, void* d_ws, size_t ws_size,
                              hipStream_t stream)
{
    const float* inputs   = (const float*)d_in[0];
    const float* inputs_p = (const float*)d_in[1];
    const float* inputs_p2= (const float*)d_in[2];
    const float* hidden   = (const float*)d_in[3];
    const float* Af       = (const float*)d_in[4];
    const float* emul     = (const float*)d_in[5];
    const float* eadd     = (const float*)d_in[6];
    const float* conv_w   = (const float*)d_in[7];
    const float* conv_b   = (const float*)d_in[8];
    const float* Wir      = (const float*)d_in[9];
    const float* bir      = (const float*)d_in[10];
    const float* Wii      = (const float*)d_in[11];
    const float* bii      = (const float*)d_in[12];
    const float* Win      = (const float*)d_in[13];
    const float* b_in     = (const float*)d_in[14];
    const float* Whr      = (const float*)d_in[15];
    const float* Whi      = (const float*)d_in[16];
    const float* Whh      = (const float*)d_in[17];
    const float* W1f      = (const float*)d_in[18];
    const float* b1f      = (const float*)d_in[19];
    const float* W2f      = (const float*)d_in[20];
    const float* b2f      = (const float*)d_in[21];
    const float* W3f      = (const float*)d_in[22];
    const float* b3f      = (const float*)d_in[23];
    float* out = (float*)d_out;

    const size_t M = M_ROWS;
    char* ws = (char*)d_ws;
    size_t off = 0;
    auto alloc = [&](size_t bytes) -> void* {
        void* p = ws + off;
        off = (off + bytes + 255) & ~(size_t)255;
        return p;
    };
    u16* hA    = (u16*)alloc(M * 256 * 2);
    u16* hB    = (u16*)alloc(M * 256 * 2);
    u16* msg   = (u16*)alloc(M * 256 * 2);
    u16* ybuf  = (u16*)alloc(M * 768 * 2);
    u16* xpad  = (u16*)alloc(M * 32 * 2);
    float* pa  = (float*)alloc(M * 3 * 4);
    float* pb  = (float*)alloc(M * 3 * 4);
    float* pc  = (float*)alloc(M * 3 * 4);
    u16* wfull = (u16*)alloc(768 * 288 * 2);
    u16* wxn   = (u16*)alloc(256 * 32 * 2);
    u16* convw = (u16*)alloc(196608 * 2);
    u16* w1    = (u16*)alloc(65536 * 2);
    u16* w2    = (u16*)alloc(65536 * 2);
    float* aadj  = (float*)alloc(KNUM * VN * VN * 4);
    float* convb = (float*)alloc(768 * 4);
    float* b1    = (float*)alloc(256 * 4);
    float* b2    = (float*)alloc(256 * 4);
    float* w3    = (float*)alloc(768 * 4);
    float* b3    = (float*)alloc(16);
    if (off > ws_size) return;

    pack_weights<<<512, 256, 0, stream>>>(
        Whr, Whi, Whh, conv_w, W1f, W2f, Af, emul, eadd, Wir, Wii, Win,
        bir, bii, b_in, conv_b, b1f, b2f, W3f, b3f,
        wfull, wxn, convw, w1, w2, aadj, convb, b1, b2, w3, b3);
    transpose_h<<<NBATCH, 256, 0, stream>>>(hidden, hA);
    init_xpad<<<M_ROWS / 256, 256, 0, stream>>>(inputs, inputs_p, inputs_p2, xpad);
    hipMemcpyAsync(pa, inputs,    M * 3 * 4, hipMemcpyDeviceToDevice, stream);
    hipMemcpyAsync(pb, inputs_p,  M * 3 * 4, hipMemcpyDeviceToDevice, stream);
    hipMemcpyAsync(pc, inputs_p2, M * 3 * 4, hipMemcpyDeviceToDevice, stream);

    u16* hcur = hA;  u16* hnext = hB;
    float* P1 = pa;  float* P2 = pb;  float* P3 = pc;
    u16* hd  = ybuf;
    u16* hd2 = ybuf + M * 256;
    const int MB = M_ROWS / 128;  // 832

    for (int s = 0; s < TS; ++s) {
        const u16* m_ptr;
        if (s < 10) {
            gemm_nt<0><<<dim3(MB, 6), 256, 0, stream>>>(hcur, convw, convb, ybuf, 768);
            graph_mix<<<NBATCH, 256, 0, stream>>>(ybuf, aadj, msg);
            m_ptr = msg;
        } else {
            m_ptr = hcur;
        }
        gru_fused<<<dim3(MB, 4), 256, 0, stream>>>(m_ptr, xpad, hcur, hnext,
                                                   wfull, wxn);
        gemm_nt<1><<<dim3(MB, 2), 256, 0, stream>>>(hnext, w1, b1, hd, 256);
        gemm_nt<1><<<dim3(MB, 2), 256, 0, stream>>>(hd, w2, b2, hd2, 256);
        // head also emits xpad for step s+1
        head_out<<<M_ROWS / 32, 256, 0, stream>>>(hd2, w3, b3, P1, P2, P3,
                                                  xpad, out, s);
        float* t = P3; P3 = P2; P2 = P1; P1 = t;
        u16* ht = hcur; hcur = hnext; hnext = ht;
    }
}